// Round 1
// baseline (567.079 us; speedup 1.0000x reference)
//
#include <hip/hip_runtime.h>

// Fused: grouped conv3x3x3 (q,k,v) -> per-location attention over depth B=5 ->
// grouped 1x1x1 proj. One thread handles one (batch, head, y, x):
//   - 8 input channels [8*hd, 8*hd+8) feed 4 q/k/v channels [4*hd, 4*hd+4)
//   - attention is 5x5 per head (seq = depth B = 5, head_dim = 4)
//   - proj produces 8 output channels [8*hd, 8*hd+8)

#define WD   128
#define HWs  (128 * 128)
#define BD   5
#define CS   (BD * HWs)   // channel stride = 81920

__global__ __launch_bounds__(256, 2)
void TCA_49177375539279_kernel(const float* __restrict__ x,
                               const float* __restrict__ last,
                               const float* __restrict__ wq,
                               const float* __restrict__ wk,
                               const float* __restrict__ wv,
                               const float* __restrict__ wp,
                               float* __restrict__ out)
{
    const int z  = blockIdx.z;
    const int bi = z >> 3;          // batch 0..7
    const int hd = z & 7;           // head 0..7
    const int px = (blockIdx.x << 6) + (threadIdx.x & 63);   // 0..127
    const int py = (blockIdx.y << 2) + (threadIdx.x >> 6);   // 0..127

    const int ch0     = hd << 3;                    // input channel base (8 ch)
    const int base_in = (bi * 64 + ch0) * CS;

    // weight layout: (oc=32, j=2, dz=3, dy=3, dx=3); head hd -> oc in [4hd,4hd+4)
    const float* __restrict__ wqb = wq + hd * 216;
    const float* __restrict__ wkb = wk + hd * 216;
    const float* __restrict__ wvb = wv + hd * 216;

    float q[4][BD], k[4][BD], v[4][BD];
#pragma unroll
    for (int c = 0; c < 4; ++c)
#pragma unroll
        for (int i = 0; i < BD; ++i) { q[c][i] = 0.f; k[c][i] = 0.f; v[c][i] = 0.f; }

    // ---------- pass 1: q = conv3x3x3(x, wq), 4 out-channels ----------
#pragma unroll 1
    for (int dy = 0; dy < 3; ++dy) {
        const int yy = py + dy - 1;
#pragma unroll
        for (int dx = 0; dx < 3; ++dx) {
            const int xx = px + dx - 1;
            const bool ok = ((unsigned)yy < 128u) && ((unsigned)xx < 128u);
            const int sp = yy * WD + xx;
            float xi[8][BD];
#pragma unroll
            for (int ic = 0; ic < 8; ++ic)
#pragma unroll
                for (int d = 0; d < BD; ++d)
                    xi[ic][d] = ok ? x[base_in + ic * CS + d * HWs + sp] : 0.f;
#pragma unroll
            for (int c = 0; c < 4; ++c)
#pragma unroll
                for (int j = 0; j < 2; ++j) {
                    const float* wr = wqb + (c * 2 + j) * 27 + dy * 3 + dx;
#pragma unroll
                    for (int dz = 0; dz < 3; ++dz) {
                        const float wgt = wr[dz * 9];
#pragma unroll
                        for (int i = 0; i < BD; ++i) {
                            const int d = i + dz - 1;      // depth pad = 1
                            if (d >= 0 && d < BD)
                                q[c][i] = fmaf(wgt, xi[c * 2 + j][d], q[c][i]);
                        }
                    }
                }
        }
    }

    // ---------- pass 2: k,v = conv3x3x3(last, wk/wv) ----------
#pragma unroll 1
    for (int dy = 0; dy < 3; ++dy) {
        const int yy = py + dy - 1;
#pragma unroll
        for (int dx = 0; dx < 3; ++dx) {
            const int xx = px + dx - 1;
            const bool ok = ((unsigned)yy < 128u) && ((unsigned)xx < 128u);
            const int sp = yy * WD + xx;
            float li[8][BD];
#pragma unroll
            for (int ic = 0; ic < 8; ++ic)
#pragma unroll
                for (int d = 0; d < BD; ++d)
                    li[ic][d] = ok ? last[base_in + ic * CS + d * HWs + sp] : 0.f;
#pragma unroll
            for (int c = 0; c < 4; ++c)
#pragma unroll
                for (int j = 0; j < 2; ++j) {
                    const float* wrk = wkb + (c * 2 + j) * 27 + dy * 3 + dx;
                    const float* wrv = wvb + (c * 2 + j) * 27 + dy * 3 + dx;
#pragma unroll
                    for (int dz = 0; dz < 3; ++dz) {
                        const float wk_ = wrk[dz * 9];
                        const float wv_ = wrv[dz * 9];
#pragma unroll
                        for (int i = 0; i < BD; ++i) {
                            const int d = i + dz - 1;
                            if (d >= 0 && d < BD) {
                                k[c][i] = fmaf(wk_, li[c * 2 + j][d], k[c][i]);
                                v[c][i] = fmaf(wv_, li[c * 2 + j][d], v[c][i]);
                            }
                        }
                    }
                }
        }
    }

    // ---------- attention: softmax_j( SCALE * q_i . k_j ) ----------
    const float SCALE = 0.35355339059327373f;   // 8^-0.5 (NUM_HEAD=8)
    float p[BD][BD];
#pragma unroll
    for (int i = 0; i < BD; ++i) {
        float s[BD];
        float m = -3.0e38f;
#pragma unroll
        for (int j = 0; j < BD; ++j) {
            float t = q[0][i] * k[0][j];
            t = fmaf(q[1][i], k[1][j], t);
            t = fmaf(q[2][i], k[2][j], t);
            t = fmaf(q[3][i], k[3][j], t);
            t *= SCALE;
            s[j] = t;
            m = fmaxf(m, t);
        }
        float sum = 0.f;
#pragma unroll
        for (int j = 0; j < BD; ++j) { float e = __expf(s[j] - m); p[i][j] = e; sum += e; }
        const float r = 1.0f / sum;
#pragma unroll
        for (int j = 0; j < BD; ++j) p[i][j] *= r;
    }

    // ---------- out = attn @ v, then 1x1 grouped proj (2 out per ch), store ----------
    const int sp0   = py * WD + px;
    const int obase = base_in + sp0;    // output has 64 ch, same base layout
#pragma unroll
    for (int c = 0; c < 4; ++c) {
        const float w0 = wp[ch0 + 2 * c];
        const float w1 = wp[ch0 + 2 * c + 1];
#pragma unroll
        for (int i = 0; i < BD; ++i) {
            float o = p[i][0] * v[c][0];
            o = fmaf(p[i][1], v[c][1], o);
            o = fmaf(p[i][2], v[c][2], o);
            o = fmaf(p[i][3], v[c][3], o);
            o = fmaf(p[i][4], v[c][4], o);
            out[obase + (2 * c)     * CS + i * HWs] = w0 * o;
            out[obase + (2 * c + 1) * CS + i * HWs] = w1 * o;
        }
    }
}

extern "C" void kernel_launch(void* const* d_in, const int* in_sizes, int n_in,
                              void* d_out, int out_size, void* d_ws, size_t ws_size,
                              hipStream_t stream)
{
    const float* x    = (const float*)d_in[0];
    const float* last = (const float*)d_in[1];
    const float* wq   = (const float*)d_in[2];
    const float* wk   = (const float*)d_in[3];
    const float* wv   = (const float*)d_in[4];
    const float* wp   = (const float*)d_in[5];
    float* out = (float*)d_out;

    dim3 grid(2, 32, 64);   // (w tiles of 64, h tiles of 4, batch*heads)
    dim3 block(256);
    hipLaunchKernelGGL(TCA_49177375539279_kernel, grid, block, 0, stream,
                       x, last, wq, wk, wv, wp, out);
}